// Round 3
// baseline (222.789 us; speedup 1.0000x reference)
//
#include <hip/hip_runtime.h>
#include <math.h>

// Problem constants
#define N_TOK 16384
#define DDIM  2048
#define NE    64
#define TK    8
#define BT    32              // tokens per block tile
#define NBLK  (N_TOK / BT)    // 512 blocks
#define KSL   256             // K per wave slice (8 slices cover 2048)
#define NST   (KSL / 16)      // 16 steps of 16 K
#define NHC   32              // histogram partial banks

// Scaling keeps fp16 split residues normal; logits scaled by 2^17, unscaled
// exactly in the epilogue.
#define XSCALE 64.0f
#define WSCALE 2048.0f
#define LUNSCALE (1.0f / 131072.0f)

// Output layout (flat concat, all fp32)
constexpr size_t OFF_TOP  = 0;
constexpr size_t OFF_SC   = (size_t)N_TOK * TK;
constexpr size_t OFF_IDX  = OFF_SC + (size_t)N_TOK * NE;
constexpr size_t OFF_HIST = OFF_IDX + (size_t)N_TOK * TK;
constexpr size_t OFF_ENT  = OFF_HIST + NE;

#define WLVL (NE * DDIM)                  // 131072 f16 per split level
#define HISTP_OFF (1u << 20)
#define ENTP_OFF  (HISTP_OFF + NHC * NE * 4)

typedef _Float16 f16x8 __attribute__((ext_vector_type(8)));
typedef float    f32x4  __attribute__((ext_vector_type(4)));
typedef float    f32x16 __attribute__((ext_vector_type(16)));

// 2-level fp16 split: v = h + m + r, |r| <= 2^-22 |v|. v - (float)h is exact.
__device__ __forceinline__ void split2(float v, _Float16& h, _Float16& m) {
    h = (_Float16)v;
    m = (_Float16)(v - (float)h);
}

__device__ __forceinline__ unsigned short f16bits(_Float16 h) {
    union { _Float16 f; unsigned short u; } c; c.f = h; return c.u;
}

// ---------------------------------------------------------------------------
// Prep: w*2048 -> 2-level fp16, 32x32x16 B-fragment-linear layout:
// frag (s16 = k/16, nt = e/32) is 64 lanes x 8 f16; lane = (k/8 % 2)*32 + e%32,
// j = k%8.  offset = ((s16*2+nt)*64 + lane)*8 + j   (+ lev*WLVL)
// ---------------------------------------------------------------------------
__global__ __launch_bounds__(64)
void prep_w(const float* __restrict__ w, unsigned short* __restrict__ wre) {
    int gid = blockIdx.x * 64 + threadIdx.x;   // 16384 threads, 8 elems each
    int e  = gid >> 8;
    int kb = gid & 255;
    int k  = kb * 8;
    const float* wp = w + (size_t)e * DDIM + k;
    float4 f0 = *(const float4*)(wp);
    float4 f1 = *(const float4*)(wp + 4);
    float av[8] = {f0.x, f0.y, f0.z, f0.w, f1.x, f1.y, f1.z, f1.w};

    int s16 = kb >> 1;                 // k/16
    int hi  = kb & 1;                  // (k/8)%2
    int nt  = e >> 5;
    int lane = hi * 32 + (e & 31);
    size_t off = ((size_t)(s16 * 2 + nt) * 64 + lane) * 8;

    unsigned short hb[8], mb[8];
    #pragma unroll
    for (int j = 0; j < 8; ++j) {
        _Float16 h, m;
        split2(av[j] * WSCALE, h, m);
        hb[j] = f16bits(h); mb[j] = f16bits(m);
    }

    #pragma unroll
    for (int lev = 0; lev < 2; ++lev) {
        const unsigned short* src = lev ? mb : hb;
        uint4 v;
        v.x = (unsigned)src[0] | ((unsigned)src[1] << 16);
        v.y = (unsigned)src[2] | ((unsigned)src[3] << 16);
        v.z = (unsigned)src[4] | ((unsigned)src[5] << 16);
        v.w = (unsigned)src[6] | ((unsigned)src[7] << 16);
        *(uint4*)(wre + (size_t)lev * WLVL + off) = v;
    }
}

// ---------------------------------------------------------------------------
// Fused GEMM + epilogue. 512 blocks x 512 threads (8 waves), 2 blocks/CU,
// 4 waves/SIMD.  Block = 32 tokens; wave w = K-slice [w*256, w*256+256).
// 32x32x16 MFMA: 2 nt fragments (64 experts), acc = 2 x f32x16.
// B straight from fragment-linear global (L2 broadcast); A depth-2 register
// ring, B depth-1 ring -- total live regs ~114, fits the 128 cap of
// __launch_bounds__(512,4) so the pipeline stays in registers.
// No barriers in the main loop; K-partials combined via LDS (fixed order).
// ---------------------------------------------------------------------------
__global__ __launch_bounds__(512, 4)
void router_fused(const float* __restrict__ x,
                  const unsigned short* __restrict__ wre,
                  const float* __restrict__ bias,
                  float* __restrict__ out,
                  int* __restrict__ histp,
                  float* __restrict__ entp)
{
    __shared__ struct {
        float pl[16][16][64];     // [w*2+nt][reg][lane] partials, 64 KB
        float sct[NE][BT + 1];    // scores [expert][token]
        float bsh[NE];
        int   hist[NE];
        float entw[2];
    } sm;                          // ~74 KB -> 2 blocks/CU

    const int tid  = threadIdx.x;
    const int lane = tid & 63;
    const int wid  = tid >> 6;      // K-slice 0..7
    const int t0b  = blockIdx.x * BT;
    const int row  = lane & 31;     // token row in A fragment
    const int hi   = lane >> 5;     // k-subgroup

    if (tid < NE) { sm.bsh[tid] = bias[tid]; sm.hist[tid] = 0; }

    const float* xp = x + (size_t)(t0b + row) * DDIM + wid * KSL + hi * 8;
    const unsigned short* wl = wre + (size_t)lane * 8;
    const int s16b = wid * NST;     // global 16-K step base

    f32x16 acc[2];
    #pragma unroll
    for (int i = 0; i < 16; ++i) { acc[0][i] = 0.f; acc[1][i] = 0.f; }

    auto loadA = [&](int s, float4 (&A)[2]) {
        A[0] = *(const float4*)(xp + s * 16);
        A[1] = *(const float4*)(xp + s * 16 + 4);
    };
    // B frags for 16-K step: [0]=bh nt0, [1]=bh nt1, [2]=bm nt0, [3]=bm nt1
    auto loadB = [&](int s, f16x8 (&B)[4]) {
        #pragma unroll
        for (int f = 0; f < 4; ++f)
            B[f] = *(const f16x8*)(wl + (size_t)(f >> 1) * WLVL
                                      + ((size_t)((s16b + s) * 2 + (f & 1)) << 9));
    };
    auto compute = [&](const float4 (&A)[2], const f16x8 (&B)[4]) {
        float av[8] = {A[0].x, A[0].y, A[0].z, A[0].w,
                       A[1].x, A[1].y, A[1].z, A[1].w};
        f16x8 ah, am;
        #pragma unroll
        for (int j = 0; j < 8; ++j) {
            _Float16 h, m;
            split2(av[j] * XSCALE, h, m);
            ah[j] = h; am[j] = m;
        }
        #pragma unroll
        for (int nt = 0; nt < 2; ++nt) {
            acc[nt] = __builtin_amdgcn_mfma_f32_32x32x16_f16(ah, B[nt],     acc[nt], 0, 0, 0);
            acc[nt] = __builtin_amdgcn_mfma_f32_32x32x16_f16(am, B[nt],     acc[nt], 0, 0, 0);
            acc[nt] = __builtin_amdgcn_mfma_f32_32x32x16_f16(ah, B[2 + nt], acc[nt], 0, 0, 0);
            acc[nt] = __builtin_amdgcn_mfma_f32_32x32x16_f16(am, B[2 + nt], acc[nt], 0, 0, 0);
        }
    };

    float4 Ab[3][2];
    f16x8  Bb[2][4];
    loadA(0, Ab[0]);
    loadA(1, Ab[1]);
    loadB(0, Bb[0]);
    #pragma unroll                  // full unroll: all ring indices constant
    for (int s = 0; s < NST; ++s) {
        if (s + 2 < NST) loadA(s + 2, Ab[(s + 2) % 3]);
        if (s + 1 < NST) loadB(s + 1, Bb[(s + 1) & 1]);
        compute(Ab[s % 3], Bb[s & 1]);
    }

    // Partials -> LDS.  C/D: col(expert%32)=lane&31, row(token)=
    // (reg&3)+8*(reg>>2)+4*(lane>>5).  Store [w*2+nt][reg][lane]: conflict-free.
    #pragma unroll
    for (int nt = 0; nt < 2; ++nt)
        #pragma unroll
        for (int r = 0; r < 16; ++r)
            sm.pl[wid * 2 + nt][r][lane] = acc[nt][r];
    __syncthreads();

    // Combine 8 K-slices (fixed order), sigmoid, score store (coalesced).
    {
        const int tok = tid >> 4;               // 0..31
        const int e0  = (tid & 15) * 4;         // 0..60
        const int nt  = e0 >> 5;
        const int r   = (tok & 3) | ((tok >> 3) << 2);
        const int ln  = ((tok >> 2) & 1) * 32 + (e0 & 31);
        f32x4 s4 = {0.f, 0.f, 0.f, 0.f};
        #pragma unroll
        for (int w = 0; w < 8; ++w)
            s4 += *(const f32x4*)&sm.pl[w * 2 + nt][r][ln];
        float4 sv;
        sv.x = 1.0f / (1.0f + expf(-s4[0] * LUNSCALE));
        sv.y = 1.0f / (1.0f + expf(-s4[1] * LUNSCALE));
        sv.z = 1.0f / (1.0f + expf(-s4[2] * LUNSCALE));
        sv.w = 1.0f / (1.0f + expf(-s4[3] * LUNSCALE));
        sm.sct[e0 + 0][tok] = sv.x;
        sm.sct[e0 + 1][tok] = sv.y;
        sm.sct[e0 + 2][tok] = sv.z;
        sm.sct[e0 + 3][tok] = sv.w;
        *(float4*)&out[OFF_SC + (size_t)(t0b + tok) * NE + e0] = sv;
    }
    __syncthreads();

    // Top-8: waves 0-1; lane = expert-group(quad) x 16 tokens.
    float entv = 0.f;
    if (wid < 2) {
        const int tl = wid * 16 + (lane & 15);
        const int eg = lane >> 4;               // expert group of 16
        float v[16];
        #pragma unroll
        for (int i = 0; i < 16; ++i)
            v[i] = sm.sct[eg * 16 + i][tl] + sm.bsh[eg * 16 + i];

        float ch[TK]; int ci[TK]; float ssum = 0.f;
        #pragma unroll
        for (int p = 0; p < TK; ++p) {
            float bv = v[0]; int bi = 0;
            #pragma unroll
            for (int i = 1; i < 16; ++i) {      // strict '>': lowest idx on tie
                const bool sgt = v[i] > bv;
                bv = sgt ? v[i] : bv;
                bi = sgt ? i : bi;
            }
            int be = eg * 16 + bi;
            {   // combine groups: lane^16 (same token, other group)
                float ov = __shfl_xor(bv, 16);
                int   oe = __shfl_xor(be, 16);
                const bool tk = (ov > bv) || (ov == bv && oe < be);
                bv = tk ? ov : bv; be = tk ? oe : be;
            }
            {   // lane^32
                float ov = __shfl_xor(bv, 32);
                int   oe = __shfl_xor(be, 32);
                const bool tk = (ov > bv) || (ov == bv && oe < be);
                bv = tk ? ov : bv; be = tk ? oe : be;
            }
            #pragma unroll
            for (int i = 0; i < 16; ++i)        // static-index mask (rule #20)
                v[i] = (be == eg * 16 + i) ? -1e30f : v[i];
            const float sc = sm.sct[be][tl];    // unbiased score
            ch[p] = sc; ci[p] = be; ssum += sc;
        }
        if (eg == 0) {
            const float inv = 1.0f / (ssum + 1e-20f);
            #pragma unroll
            for (int p = 0; p < TK; ++p) {
                atomicAdd(&sm.hist[ci[p]], 1);
                const float pn = ch[p] * inv;   // ROUTE_SCALE == 1.0
                out[OFF_TOP + (size_t)(t0b + tl) * TK + p] = pn;
                out[OFF_IDX + (size_t)(t0b + tl) * TK + p] = (float)ci[p];
                entv += pn * logf(pn);
            }
        }
        entv += __shfl_down(entv, 8);
        entv += __shfl_down(entv, 4);
        entv += __shfl_down(entv, 2);
        entv += __shfl_down(entv, 1);
        if (lane == 0) sm.entw[wid] = entv;
    }
    __syncthreads();

    if (tid == 0) entp[blockIdx.x] = sm.entw[0] + sm.entw[1];
    if (tid < NE && sm.hist[tid] > 0)
        atomicAdd(&histp[(blockIdx.x & (NHC - 1)) * NE + tid], sm.hist[tid]);
}

// ---------------------------------------------------------------------------
// Finalize: reduce histogram banks and entropy partials (deterministic)
// ---------------------------------------------------------------------------
__global__ __launch_bounds__(256)
void finalize(const int* __restrict__ histp,
              const float* __restrict__ entp,
              float* __restrict__ out)
{
    const int tid = threadIdx.x;
    if (tid < NE) {
        int s = 0;
        #pragma unroll
        for (int c = 0; c < NHC; ++c) s += histp[c * NE + tid];
        out[OFF_HIST + tid] = (float)s;
    }
    __shared__ float red[256];
    float e = 0.f;
    for (int i = tid; i < NBLK; i += 256) e += entp[i];
    red[tid] = e;
    __syncthreads();
    #pragma unroll
    for (int o = 128; o > 0; o >>= 1) {
        if (tid < o) red[tid] += red[tid + o];
        __syncthreads();
    }
    if (tid == 0) out[OFF_ENT] = -red[0] * (1.0f / (float)N_TOK);
}

extern "C" void kernel_launch(void* const* d_in, const int* in_sizes, int n_in,
                              void* d_out, int out_size, void* d_ws, size_t ws_size,
                              hipStream_t stream) {
    const float* x    = (const float*)d_in[0];   // [16384, 2048]
    const float* w    = (const float*)d_in[1];   // [64, 2048]
    const float* bias = (const float*)d_in[2];   // [64]
    float* out = (float*)d_out;
    unsigned short* wre = (unsigned short*)d_ws;            // 512 KB (2 levels)
    int*   histp = (int*)  ((char*)d_ws + HISTP_OFF);
    float* entp  = (float*)((char*)d_ws + ENTP_OFF);

    hipMemsetAsync(histp, 0, NHC * NE * sizeof(int), stream);

    prep_w      <<<dim3(256),  dim3(64),  0, stream>>>(w, wre);
    router_fused<<<dim3(NBLK), dim3(512), 0, stream>>>(x, wre, bias, out, histp, entp);
    finalize    <<<dim3(1),    dim3(256), 0, stream>>>(histp, entp, out);
}

// Round 4
// 218.789 us; speedup vs baseline: 1.0183x; 1.0183x over previous
//
#include <hip/hip_runtime.h>
#include <math.h>

// Problem constants
#define N_TOK 16384
#define DDIM  2048
#define NE    64
#define TK    8
#define BT    32              // tokens per block tile
#define NBLK  (N_TOK / BT)    // 512 blocks
#define KSL   256             // K per wave slice (8 slices cover 2048)
#define NST   (KSL / 16)      // 16 steps of 16 K
#define NHC   32              // histogram partial banks

// Scaling keeps fp16 split residues normal; logits scaled by 2^17, unscaled
// exactly in the epilogue.
#define XSCALE 64.0f
#define WSCALE 2048.0f
#define LUNSCALE (1.0f / 131072.0f)

// Output layout (flat concat, all fp32)
constexpr size_t OFF_TOP  = 0;
constexpr size_t OFF_SC   = (size_t)N_TOK * TK;
constexpr size_t OFF_IDX  = OFF_SC + (size_t)N_TOK * NE;
constexpr size_t OFF_HIST = OFF_IDX + (size_t)N_TOK * TK;
constexpr size_t OFF_ENT  = OFF_HIST + NE;

#define WLVL (NE * DDIM)                  // 131072 f16 per split level
#define HISTP_OFF (1u << 20)
#define ENTP_OFF  (HISTP_OFF + NHC * NE * 4)

typedef _Float16 f16x8 __attribute__((ext_vector_type(8)));
typedef float    f32x4  __attribute__((ext_vector_type(4)));
typedef float    f32x16 __attribute__((ext_vector_type(16)));

// 2-level fp16 split: v = h + m + r, |r| <= 2^-22 |v|. v - (float)h is exact.
__device__ __forceinline__ void split2(float v, _Float16& h, _Float16& m) {
    h = (_Float16)v;
    m = (_Float16)(v - (float)h);
}

__device__ __forceinline__ unsigned short f16bits(_Float16 h) {
    union { _Float16 f; unsigned short u; } c; c.f = h; return c.u;
}

// ---------------------------------------------------------------------------
// Prep: w*2048 -> 2-level fp16, 32x32x16 B-fragment-linear layout:
// frag (s16 = k/16, nt = e/32) is 64 lanes x 8 f16; lane = (k/8 % 2)*32 + e%32,
// j = k%8.  offset = ((s16*2+nt)*64 + lane)*8 + j   (+ lev*WLVL)
// ---------------------------------------------------------------------------
__global__ __launch_bounds__(64)
void prep_w(const float* __restrict__ w, unsigned short* __restrict__ wre) {
    int gid = blockIdx.x * 64 + threadIdx.x;   // 16384 threads, 8 elems each
    int e  = gid >> 8;
    int kb = gid & 255;
    int k  = kb * 8;
    const float* wp = w + (size_t)e * DDIM + k;
    float4 f0 = *(const float4*)(wp);
    float4 f1 = *(const float4*)(wp + 4);
    float av[8] = {f0.x, f0.y, f0.z, f0.w, f1.x, f1.y, f1.z, f1.w};

    int s16 = kb >> 1;                 // k/16
    int hi  = kb & 1;                  // (k/8)%2
    int nt  = e >> 5;
    int lane = hi * 32 + (e & 31);
    size_t off = ((size_t)(s16 * 2 + nt) * 64 + lane) * 8;

    unsigned short hb[8], mb[8];
    #pragma unroll
    for (int j = 0; j < 8; ++j) {
        _Float16 h, m;
        split2(av[j] * WSCALE, h, m);
        hb[j] = f16bits(h); mb[j] = f16bits(m);
    }

    #pragma unroll
    for (int lev = 0; lev < 2; ++lev) {
        const unsigned short* src = lev ? mb : hb;
        uint4 v;
        v.x = (unsigned)src[0] | ((unsigned)src[1] << 16);
        v.y = (unsigned)src[2] | ((unsigned)src[3] << 16);
        v.z = (unsigned)src[4] | ((unsigned)src[5] << 16);
        v.w = (unsigned)src[6] | ((unsigned)src[7] << 16);
        *(uint4*)(wre + (size_t)lev * WLVL + off) = v;
    }
}

// ---------------------------------------------------------------------------
// Fused GEMM + epilogue. 512 blocks x 512 threads (8 waves), 2 blocks/CU,
// 4 waves/SIMD.  Block = 32 tokens; wave w = K-slice [w*256, w*256+256).
// 32x32x16 MFMA: 2 nt fragments (64 experts), acc = 2 x f32x16.
//
// PIPELINE IS FORCED: each unrolled step issues next-step B (+1) and A (+2)
// loads first, then sched_barrier(0) pins them above the compute block --
// the scheduler cannot sink prefetch loads to their uses (the R2 failure:
// VGPR_Count=76 proved the written ring was collapsed to just-in-time
// loads).  Compiler then emits counted vmcnt waits at first use; ~6 loads
// per wave stay in flight -> ~24 KB outstanding per CU > the 22 KB needed
// to sustain the 24.6 GB/s/CU HBM share.
// ---------------------------------------------------------------------------
__global__ __launch_bounds__(512, 4)
void router_fused(const float* __restrict__ x,
                  const unsigned short* __restrict__ wre,
                  const float* __restrict__ bias,
                  float* __restrict__ out,
                  int* __restrict__ histp,
                  float* __restrict__ entp)
{
    __shared__ struct {
        float pl[16][16][64];     // [w*2+nt][reg][lane] partials, 64 KB
        float sct[NE][BT + 1];    // scores [expert][token]
        float bsh[NE];
        int   hist[NE];
        float entw[2];
    } sm;                          // ~74 KB -> 2 blocks/CU

    const int tid  = threadIdx.x;
    const int lane = tid & 63;
    const int wid  = tid >> 6;      // K-slice 0..7
    const int t0b  = blockIdx.x * BT;
    const int row  = lane & 31;     // token row in A fragment
    const int hi   = lane >> 5;     // k-subgroup

    if (tid < NE) { sm.bsh[tid] = bias[tid]; sm.hist[tid] = 0; }

    const float* xp = x + (size_t)(t0b + row) * DDIM + wid * KSL + hi * 8;
    const unsigned short* wl = wre + (size_t)lane * 8;
    const int s16b = wid * NST;     // global 16-K step base

    f32x16 acc[2];
    #pragma unroll
    for (int i = 0; i < 16; ++i) { acc[0][i] = 0.f; acc[1][i] = 0.f; }

    auto loadA = [&](int s, float4 (&A)[2]) {
        A[0] = *(const float4*)(xp + s * 16);
        A[1] = *(const float4*)(xp + s * 16 + 4);
    };
    // B frags for 16-K step: [0]=bh nt0, [1]=bh nt1, [2]=bm nt0, [3]=bm nt1
    auto loadB = [&](int s, f16x8 (&B)[4]) {
        #pragma unroll
        for (int f = 0; f < 4; ++f)
            B[f] = *(const f16x8*)(wl + (size_t)(f >> 1) * WLVL
                                      + ((size_t)((s16b + s) * 2 + (f & 1)) << 9));
    };
    auto compute = [&](const float4 (&A)[2], const f16x8 (&B)[4]) {
        float av[8] = {A[0].x, A[0].y, A[0].z, A[0].w,
                       A[1].x, A[1].y, A[1].z, A[1].w};
        f16x8 ah, am;
        #pragma unroll
        for (int j = 0; j < 8; ++j) {
            _Float16 h, m;
            split2(av[j] * XSCALE, h, m);
            ah[j] = h; am[j] = m;
        }
        #pragma unroll
        for (int nt = 0; nt < 2; ++nt) {
            acc[nt] = __builtin_amdgcn_mfma_f32_32x32x16_f16(ah, B[nt],     acc[nt], 0, 0, 0);
            acc[nt] = __builtin_amdgcn_mfma_f32_32x32x16_f16(am, B[nt],     acc[nt], 0, 0, 0);
            acc[nt] = __builtin_amdgcn_mfma_f32_32x32x16_f16(ah, B[2 + nt], acc[nt], 0, 0, 0);
            acc[nt] = __builtin_amdgcn_mfma_f32_32x32x16_f16(am, B[2 + nt], acc[nt], 0, 0, 0);
        }
    };

    float4 Ab[3][2];
    f16x8  Bb[2][4];
    loadA(0, Ab[0]);
    loadB(0, Bb[0]);
    loadA(1, Ab[1]);
    __builtin_amdgcn_sched_barrier(0);   // prologue loads stay first
    #pragma unroll                       // full unroll: ring indices constant
    for (int s = 0; s < NST; ++s) {
        // Issue next-step loads FIRST...
        if (s + 1 < NST) loadB(s + 1, Bb[(s + 1) & 1]);
        if (s + 2 < NST) loadA(s + 2, Ab[(s + 2) % 3]);
        // ...and pin them above the compute: they may NOT sink to their uses.
        __builtin_amdgcn_sched_barrier(0);
        compute(Ab[s % 3], Bb[s & 1]);
    }

    // Partials -> LDS.  C/D: col(expert%32)=lane&31, row(token)=
    // (reg&3)+8*(reg>>2)+4*(lane>>5).  Store [w*2+nt][reg][lane]: conflict-free.
    #pragma unroll
    for (int nt = 0; nt < 2; ++nt)
        #pragma unroll
        for (int r = 0; r < 16; ++r)
            sm.pl[wid * 2 + nt][r][lane] = acc[nt][r];
    __syncthreads();

    // Combine 8 K-slices (fixed order), sigmoid, score store (coalesced).
    {
        const int tok = tid >> 4;               // 0..31
        const int e0  = (tid & 15) * 4;         // 0..60
        const int nt  = e0 >> 5;
        const int r   = (tok & 3) | ((tok >> 3) << 2);
        const int ln  = ((tok >> 2) & 1) * 32 + (e0 & 31);
        f32x4 s4 = {0.f, 0.f, 0.f, 0.f};
        #pragma unroll
        for (int w = 0; w < 8; ++w)
            s4 += *(const f32x4*)&sm.pl[w * 2 + nt][r][ln];
        float4 sv;
        sv.x = 1.0f / (1.0f + expf(-s4[0] * LUNSCALE));
        sv.y = 1.0f / (1.0f + expf(-s4[1] * LUNSCALE));
        sv.z = 1.0f / (1.0f + expf(-s4[2] * LUNSCALE));
        sv.w = 1.0f / (1.0f + expf(-s4[3] * LUNSCALE));
        sm.sct[e0 + 0][tok] = sv.x;
        sm.sct[e0 + 1][tok] = sv.y;
        sm.sct[e0 + 2][tok] = sv.z;
        sm.sct[e0 + 3][tok] = sv.w;
        *(float4*)&out[OFF_SC + (size_t)(t0b + tok) * NE + e0] = sv;
    }
    __syncthreads();

    // Top-8: waves 0-1; lane = expert-group(quad) x 16 tokens.
    float entv = 0.f;
    if (wid < 2) {
        const int tl = wid * 16 + (lane & 15);
        const int eg = lane >> 4;               // expert group of 16
        float v[16];
        #pragma unroll
        for (int i = 0; i < 16; ++i)
            v[i] = sm.sct[eg * 16 + i][tl] + sm.bsh[eg * 16 + i];

        float ch[TK]; int ci[TK]; float ssum = 0.f;
        #pragma unroll
        for (int p = 0; p < TK; ++p) {
            float bv = v[0]; int bi = 0;
            #pragma unroll
            for (int i = 1; i < 16; ++i) {      // strict '>': lowest idx on tie
                const bool sgt = v[i] > bv;
                bv = sgt ? v[i] : bv;
                bi = sgt ? i : bi;
            }
            int be = eg * 16 + bi;
            {   // combine groups: lane^16 (same token, other group)
                float ov = __shfl_xor(bv, 16);
                int   oe = __shfl_xor(be, 16);
                const bool tk = (ov > bv) || (ov == bv && oe < be);
                bv = tk ? ov : bv; be = tk ? oe : be;
            }
            {   // lane^32
                float ov = __shfl_xor(bv, 32);
                int   oe = __shfl_xor(be, 32);
                const bool tk = (ov > bv) || (ov == bv && oe < be);
                bv = tk ? ov : bv; be = tk ? oe : be;
            }
            #pragma unroll
            for (int i = 0; i < 16; ++i)        // static-index mask (rule #20)
                v[i] = (be == eg * 16 + i) ? -1e30f : v[i];
            const float sc = sm.sct[be][tl];    // unbiased score
            ch[p] = sc; ci[p] = be; ssum += sc;
        }
        if (eg == 0) {
            const float inv = 1.0f / (ssum + 1e-20f);
            #pragma unroll
            for (int p = 0; p < TK; ++p) {
                atomicAdd(&sm.hist[ci[p]], 1);
                const float pn = ch[p] * inv;   // ROUTE_SCALE == 1.0
                out[OFF_TOP + (size_t)(t0b + tl) * TK + p] = pn;
                out[OFF_IDX + (size_t)(t0b + tl) * TK + p] = (float)ci[p];
                entv += pn * logf(pn);
            }
        }
        entv += __shfl_down(entv, 8);
        entv += __shfl_down(entv, 4);
        entv += __shfl_down(entv, 2);
        entv += __shfl_down(entv, 1);
        if (lane == 0) sm.entw[wid] = entv;
    }
    __syncthreads();

    if (tid == 0) entp[blockIdx.x] = sm.entw[0] + sm.entw[1];
    if (tid < NE && sm.hist[tid] > 0)
        atomicAdd(&histp[(blockIdx.x & (NHC - 1)) * NE + tid], sm.hist[tid]);
}

// ---------------------------------------------------------------------------
// Finalize: reduce histogram banks and entropy partials (deterministic)
// ---------------------------------------------------------------------------
__global__ __launch_bounds__(256)
void finalize(const int* __restrict__ histp,
              const float* __restrict__ entp,
              float* __restrict__ out)
{
    const int tid = threadIdx.x;
    if (tid < NE) {
        int s = 0;
        #pragma unroll
        for (int c = 0; c < NHC; ++c) s += histp[c * NE + tid];
        out[OFF_HIST + tid] = (float)s;
    }
    __shared__ float red[256];
    float e = 0.f;
    for (int i = tid; i < NBLK; i += 256) e += entp[i];
    red[tid] = e;
    __syncthreads();
    #pragma unroll
    for (int o = 128; o > 0; o >>= 1) {
        if (tid < o) red[tid] += red[tid + o];
        __syncthreads();
    }
    if (tid == 0) out[OFF_ENT] = -red[0] * (1.0f / (float)N_TOK);
}

extern "C" void kernel_launch(void* const* d_in, const int* in_sizes, int n_in,
                              void* d_out, int out_size, void* d_ws, size_t ws_size,
                              hipStream_t stream) {
    const float* x    = (const float*)d_in[0];   // [16384, 2048]
    const float* w    = (const float*)d_in[1];   // [64, 2048]
    const float* bias = (const float*)d_in[2];   // [64]
    float* out = (float*)d_out;
    unsigned short* wre = (unsigned short*)d_ws;            // 512 KB (2 levels)
    int*   histp = (int*)  ((char*)d_ws + HISTP_OFF);
    float* entp  = (float*)((char*)d_ws + ENTP_OFF);

    hipMemsetAsync(histp, 0, NHC * NE * sizeof(int), stream);

    prep_w      <<<dim3(256),  dim3(64),  0, stream>>>(w, wre);
    router_fused<<<dim3(NBLK), dim3(512), 0, stream>>>(x, wre, bias, out, histp, entp);
    finalize    <<<dim3(1),    dim3(256), 0, stream>>>(histp, entp, out);
}

// Round 6
// 216.105 us; speedup vs baseline: 1.0309x; 1.0124x over previous
//
#include <hip/hip_runtime.h>
#include <math.h>

// Problem constants
#define N_TOK 16384
#define DDIM  2048
#define NE    64
#define TK    8
#define BT    32              // tokens per block tile
#define NBLK  (N_TOK / BT)    // 512 blocks
#define KSL   256             // K per wave slice (8 slices cover 2048)
#define NST   (KSL / 16)      // 16 steps of 16 K
#define NCH   8               // chunks per wave slice (32 K each)
#define NHC   32              // histogram partial banks

// Scaling keeps fp16 split residues normal; logits scaled by 2^17, unscaled
// exactly in the epilogue.
#define XSCALE 64.0f
#define WSCALE 2048.0f
#define LUNSCALE (1.0f / 131072.0f)

// Output layout (flat concat, all fp32)
constexpr size_t OFF_TOP  = 0;
constexpr size_t OFF_SC   = (size_t)N_TOK * TK;
constexpr size_t OFF_IDX  = OFF_SC + (size_t)N_TOK * NE;
constexpr size_t OFF_HIST = OFF_IDX + (size_t)N_TOK * TK;
constexpr size_t OFF_ENT  = OFF_HIST + NE;

#define WLVL (NE * DDIM)                  // 131072 f16 per split level
#define HISTP_OFF (1u << 20)
#define ENTP_OFF  (HISTP_OFF + NHC * NE * 4)

typedef _Float16 f16x8 __attribute__((ext_vector_type(8)));
typedef float    f32x4  __attribute__((ext_vector_type(4)));
typedef float    f32x16 __attribute__((ext_vector_type(16)));

typedef const __attribute__((address_space(1))) unsigned int gu32;
typedef       __attribute__((address_space(3))) unsigned int lu32;

// 2-level fp16 split: v = h + m + r, |r| <= 2^-22 |v|. v - (float)h is exact.
__device__ __forceinline__ void split2(float v, _Float16& h, _Float16& m) {
    h = (_Float16)v;
    m = (_Float16)(v - (float)h);
}

__device__ __forceinline__ unsigned short f16bits(_Float16 h) {
    union { _Float16 f; unsigned short u; } c; c.f = h; return c.u;
}

// ---------------------------------------------------------------------------
// Prep: w*2048 -> 2-level fp16, 32x32x16 B-fragment-linear layout:
// frag (s16 = k/16, nt = e/32) is 64 lanes x 8 f16; lane = (k/8 % 2)*32 + e%32,
// j = k%8.  offset = ((s16*2+nt)*64 + lane)*8 + j   (+ lev*WLVL)
// ---------------------------------------------------------------------------
__global__ __launch_bounds__(64)
void prep_w(const float* __restrict__ w, unsigned short* __restrict__ wre) {
    int gid = blockIdx.x * 64 + threadIdx.x;   // 16384 threads, 8 elems each
    int e  = gid >> 8;
    int kb = gid & 255;
    int k  = kb * 8;
    const float* wp = w + (size_t)e * DDIM + k;
    float4 f0 = *(const float4*)(wp);
    float4 f1 = *(const float4*)(wp + 4);
    float av[8] = {f0.x, f0.y, f0.z, f0.w, f1.x, f1.y, f1.z, f1.w};

    int s16 = kb >> 1;                 // k/16
    int hi  = kb & 1;                  // (k/8)%2
    int nt  = e >> 5;
    int lane = hi * 32 + (e & 31);
    size_t off = ((size_t)(s16 * 2 + nt) * 64 + lane) * 8;

    unsigned short hb[8], mb[8];
    #pragma unroll
    for (int j = 0; j < 8; ++j) {
        _Float16 h, m;
        split2(av[j] * WSCALE, h, m);
        hb[j] = f16bits(h); mb[j] = f16bits(m);
    }

    #pragma unroll
    for (int lev = 0; lev < 2; ++lev) {
        const unsigned short* src = lev ? mb : hb;
        uint4 v;
        v.x = (unsigned)src[0] | ((unsigned)src[1] << 16);
        v.y = (unsigned)src[2] | ((unsigned)src[3] << 16);
        v.z = (unsigned)src[4] | ((unsigned)src[5] << 16);
        v.w = (unsigned)src[6] | ((unsigned)src[7] << 16);
        *(uint4*)(wre + (size_t)lev * WLVL + off) = v;
    }
}

// ---------------------------------------------------------------------------
// Fused GEMM + epilogue. 512 blocks x 512 threads (8 waves), 2 blocks/CU,
// 4 waves/SIMD.  Block = 32 tokens; wave w = K-slice [w*256, w*256+256).
//
// A is staged via global_load_lds DMA (fire-and-forget, no VGPR cost):
// chunk c stages, for EVERY wave w, its next 32-K window -> 8 slabs x 4 KB
// = 32 KB/chunk, double-buffered.  T3 minimum 2-phase: issue stage(c+1)
// BEFORE computing chunk c; one barrier per chunk (its vmcnt(0) drain IS
// the wait for chunk c+1).  In-flight per CU = 2 blocks x 32 KB = 64 KB >>
// the ~9 KB needed to saturate the per-CU HBM share -- this is what the
// register-ring versions could never do (R2/R3: VGPR_Count=76, compiler
// collapsed the ring; R2 L3-warm still 79us = pure latency-bound).
//
// Slab layout g-major: slot = g*32 + t (t = lane&31 = MFMA row, g = 16B
// granule = 4 K).  gload_lds linear dest (base + lane*16) matches source
// x[t0b + (l&31)][w*256 + c*32 + (2i + (l>>5))*4] exactly.
// ---------------------------------------------------------------------------
__global__ __launch_bounds__(512, 4)
void router_fused(const float* __restrict__ x,
                  const unsigned short* __restrict__ wre,
                  const float* __restrict__ bias,
                  float* __restrict__ out,
                  int* __restrict__ histp,
                  float* __restrict__ entp)
{
    union SMem {
        float As[2][8192];            // [buf][wid*1024 + slot*4f], 64 KB
        struct {
            float pl[16][16][64];     // [w*2+nt][reg][lane] partials, 64 KB
            float sct[NE][BT + 1];    // scores [expert][token]
            float bsh[NE];
            int   hist[NE];
            float entw[2];
        } ep;                          // ~74.5 KB -> 2 blocks/CU
    };
    __shared__ SMem sm;

    const int tid  = threadIdx.x;
    const int lane = tid & 63;
    const int wid  = tid >> 6;      // K-slice 0..7
    const int t0b  = blockIdx.x * BT;
    const int row  = lane & 31;     // token row in A fragment (= staging t)
    const int hi   = lane >> 5;     // k-subgroup (= staging granule parity)

    if (tid < NE) { sm.ep.bsh[tid] = bias[tid]; sm.ep.hist[tid] = 0; }

    const float* xsrc = x + (size_t)(t0b + row) * DDIM + wid * KSL;
    const unsigned short* wl = wre + (size_t)lane * 8;
    const int s16b = wid * NST;     // global 16-K step base

    f32x16 acc[2];
    #pragma unroll
    for (int i = 0; i < 16; ++i) { acc[0][i] = 0.f; acc[1][i] = 0.f; }

    // Stage chunk c into buffer buf: wave wid stages its own 4 KB slab as
    // 4 x 1 KB rounds.  Lane l -> slot i*64+l = (g*32+t): t=l&31, g=2i+(l>>5).
    auto stage = [&](int c, int buf) {
        #pragma unroll
        for (int i = 0; i < 4; ++i) {
            const float* g = xsrc + c * 32 + (i * 2 + hi) * 4;
            __builtin_amdgcn_global_load_lds((gu32*)g,
                (lu32*)&sm.As[buf][wid * 1024 + i * 256], 16, 0, 0);
        }
    };
    // B frags for 16-K step: [0]=bh nt0, [1]=bh nt1, [2]=bm nt0, [3]=bm nt1
    auto loadB = [&](int s, f16x8 (&B)[4]) {
        #pragma unroll
        for (int f = 0; f < 4; ++f)
            B[f] = *(const f16x8*)(wl + (size_t)(f >> 1) * WLVL
                                      + ((size_t)((s16b + s) * 2 + (f & 1)) << 9));
    };

    stage(0, 0);
    __syncthreads();                 // vmcnt(0) drain: chunk 0 resident

    #pragma unroll
    for (int c = 0; c < NCH; ++c) {
        const int buf = c & 1;
        if (c + 1 < NCH) stage(c + 1, buf ^ 1);   // issue BEFORE compute
        __builtin_amdgcn_sched_barrier(0);         // pin issue above compute
        const float4* As4 = (const float4*)&sm.As[buf][wid * 1024];
        #pragma unroll
        for (int s = 0; s < 2; ++s) {              // 2 x 16-K steps per chunk
            f16x8 B[4];
            loadB(c * 2 + s, B);
            const int g0 = s * 4 + hi * 2;
            float4 G0 = As4[g0 * 32 + row];        // ds_read_b128
            float4 G1 = As4[(g0 + 1) * 32 + row];
            float av[8] = {G0.x, G0.y, G0.z, G0.w, G1.x, G1.y, G1.z, G1.w};
            f16x8 ah, am;
            #pragma unroll
            for (int j = 0; j < 8; ++j) {
                _Float16 h, m;
                split2(av[j] * XSCALE, h, m);
                ah[j] = h; am[j] = m;
            }
            #pragma unroll
            for (int nt = 0; nt < 2; ++nt) {
                acc[nt] = __builtin_amdgcn_mfma_f32_32x32x16_f16(ah, B[nt],     acc[nt], 0, 0, 0);
                acc[nt] = __builtin_amdgcn_mfma_f32_32x32x16_f16(am, B[nt],     acc[nt], 0, 0, 0);
                acc[nt] = __builtin_amdgcn_mfma_f32_32x32x16_f16(ah, B[2 + nt], acc[nt], 0, 0, 0);
                acc[nt] = __builtin_amdgcn_mfma_f32_32x32x16_f16(am, B[2 + nt], acc[nt], 0, 0, 0);
            }
        }
        __syncthreads();             // one drain/chunk: waits chunk c+1 DMA
    }

    // ---- epilogue (As dead; pl overlays it) ----
    // C/D: col(expert%32)=lane&31, row(token)=(reg&3)+8*(reg>>2)+4*(lane>>5).
    #pragma unroll
    for (int nt = 0; nt < 2; ++nt)
        #pragma unroll
        for (int r = 0; r < 16; ++r)
            sm.ep.pl[wid * 2 + nt][r][lane] = acc[nt][r];
    __syncthreads();

    // Combine 8 K-slices (fixed order), sigmoid, score store (coalesced).
    {
        const int tok = tid >> 4;               // 0..31
        const int e0  = (tid & 15) * 4;         // 0..60
        const int nt  = e0 >> 5;
        const int r   = (tok & 3) | ((tok >> 3) << 2);
        const int ln  = ((tok >> 2) & 1) * 32 + (e0 & 31);
        f32x4 s4 = {0.f, 0.f, 0.f, 0.f};
        #pragma unroll
        for (int w = 0; w < 8; ++w)
            s4 += *(const f32x4*)&sm.ep.pl[w * 2 + nt][r][ln];
        float4 sv;
        sv.x = 1.0f / (1.0f + expf(-s4[0] * LUNSCALE));
        sv.y = 1.0f / (1.0f + expf(-s4[1] * LUNSCALE));
        sv.z = 1.0f / (1.0f + expf(-s4[2] * LUNSCALE));
        sv.w = 1.0f / (1.0f + expf(-s4[3] * LUNSCALE));
        sm.ep.sct[e0 + 0][tok] = sv.x;
        sm.ep.sct[e0 + 1][tok] = sv.y;
        sm.ep.sct[e0 + 2][tok] = sv.z;
        sm.ep.sct[e0 + 3][tok] = sv.w;
        *(float4*)&out[OFF_SC + (size_t)(t0b + tok) * NE + e0] = sv;
    }
    __syncthreads();

    // Top-8: waves 0-1; lane = expert-group x 16 tokens.
    float entv = 0.f;
    if (wid < 2) {
        const int tl = wid * 16 + (lane & 15);
        const int eg = lane >> 4;               // expert group of 16
        float v[16];
        #pragma unroll
        for (int i = 0; i < 16; ++i)
            v[i] = sm.ep.sct[eg * 16 + i][tl] + sm.ep.bsh[eg * 16 + i];

        float ch[TK]; int ci[TK]; float ssum = 0.f;
        #pragma unroll
        for (int p = 0; p < TK; ++p) {
            float bv = v[0]; int bi = 0;
            #pragma unroll
            for (int i = 1; i < 16; ++i) {      // strict '>': lowest idx on tie
                const bool sgt = v[i] > bv;
                bv = sgt ? v[i] : bv;
                bi = sgt ? i : bi;
            }
            int be = eg * 16 + bi;
            {   // combine groups: lane^16 (same token, other group)
                float ov = __shfl_xor(bv, 16);
                int   oe = __shfl_xor(be, 16);
                const bool tk = (ov > bv) || (ov == bv && oe < be);
                bv = tk ? ov : bv; be = tk ? oe : be;
            }
            {   // lane^32
                float ov = __shfl_xor(bv, 32);
                int   oe = __shfl_xor(be, 32);
                const bool tk = (ov > bv) || (ov == bv && oe < be);
                bv = tk ? ov : bv; be = tk ? oe : be;
            }
            #pragma unroll
            for (int i = 0; i < 16; ++i)        // static-index mask (rule #20)
                v[i] = (be == eg * 16 + i) ? -1e30f : v[i];
            const float sc = sm.ep.sct[be][tl]; // unbiased score
            ch[p] = sc; ci[p] = be; ssum += sc;
        }
        if (eg == 0) {
            const float inv = 1.0f / (ssum + 1e-20f);
            #pragma unroll
            for (int p = 0; p < TK; ++p) {
                atomicAdd(&sm.ep.hist[ci[p]], 1);
                const float pn = ch[p] * inv;   // ROUTE_SCALE == 1.0
                out[OFF_TOP + (size_t)(t0b + tl) * TK + p] = pn;
                out[OFF_IDX + (size_t)(t0b + tl) * TK + p] = (float)ci[p];
                entv += pn * logf(pn);
            }
        }
        entv += __shfl_down(entv, 8);
        entv += __shfl_down(entv, 4);
        entv += __shfl_down(entv, 2);
        entv += __shfl_down(entv, 1);
        if (lane == 0) sm.ep.entw[wid] = entv;
    }
    __syncthreads();

    if (tid == 0) entp[blockIdx.x] = sm.ep.entw[0] + sm.ep.entw[1];
    if (tid < NE && sm.ep.hist[tid] > 0)
        atomicAdd(&histp[(blockIdx.x & (NHC - 1)) * NE + tid], sm.ep.hist[tid]);
}

// ---------------------------------------------------------------------------
// Finalize: reduce histogram banks and entropy partials (deterministic)
// ---------------------------------------------------------------------------
__global__ __launch_bounds__(256)
void finalize(const int* __restrict__ histp,
              const float* __restrict__ entp,
              float* __restrict__ out)
{
    const int tid = threadIdx.x;
    if (tid < NE) {
        int s = 0;
        #pragma unroll
        for (int c = 0; c < NHC; ++c) s += histp[c * NE + tid];
        out[OFF_HIST + tid] = (float)s;
    }
    __shared__ float red[256];
    float e = 0.f;
    for (int i = tid; i < NBLK; i += 256) e += entp[i];
    red[tid] = e;
    __syncthreads();
    #pragma unroll
    for (int o = 128; o > 0; o >>= 1) {
        if (tid < o) red[tid] += red[tid + o];
        __syncthreads();
    }
    if (tid == 0) out[OFF_ENT] = -red[0] * (1.0f / (float)N_TOK);
}

extern "C" void kernel_launch(void* const* d_in, const int* in_sizes, int n_in,
                              void* d_out, int out_size, void* d_ws, size_t ws_size,
                              hipStream_t stream) {
    const float* x    = (const float*)d_in[0];   // [16384, 2048]
    const float* w    = (const float*)d_in[1];   // [64, 2048]
    const float* bias = (const float*)d_in[2];   // [64]
    float* out = (float*)d_out;
    unsigned short* wre = (unsigned short*)d_ws;            // 512 KB (2 levels)
    int*   histp = (int*)  ((char*)d_ws + HISTP_OFF);
    float* entp  = (float*)((char*)d_ws + ENTP_OFF);

    hipMemsetAsync(histp, 0, NHC * NE * sizeof(int), stream);

    prep_w      <<<dim3(256),  dim3(64),  0, stream>>>(w, wre);
    router_fused<<<dim3(NBLK), dim3(512), 0, stream>>>(x, wre, bias, out, histp, entp);
    finalize    <<<dim3(1),    dim3(256), 0, stream>>>(histp, entp, out);
}

// Round 7
// 208.970 us; speedup vs baseline: 1.0661x; 1.0341x over previous
//
#include <hip/hip_runtime.h>
#include <math.h>

// Problem constants
#define N_TOK 16384
#define DDIM  2048
#define NE    64
#define TK    8
#define BT    32              // tokens per block tile
#define NBLK  (N_TOK / BT)    // 512 blocks
#define KSL   256             // K per wave slice (8 slices cover 2048)
#define NST   (KSL / 16)      // 16 steps of 16 K
#define NCH   8               // chunks per wave slice (32 K each)
#define NHC   32              // histogram partial banks

// Scaling keeps fp16 split residues normal; logits scaled by 2^17, unscaled
// exactly in the epilogue.
#define XSCALE 64.0f
#define WSCALE 2048.0f
#define LUNSCALE (1.0f / 131072.0f)

// Output layout (flat concat, all fp32)
constexpr size_t OFF_TOP  = 0;
constexpr size_t OFF_SC   = (size_t)N_TOK * TK;
constexpr size_t OFF_IDX  = OFF_SC + (size_t)N_TOK * NE;
constexpr size_t OFF_HIST = OFF_IDX + (size_t)N_TOK * TK;
constexpr size_t OFF_ENT  = OFF_HIST + NE;

#define WLVL (NE * DDIM)                  // 131072 f16 per split level
#define HISTP_OFF (1u << 20)
#define ENTP_OFF  (HISTP_OFF + NHC * NE * 4)

typedef _Float16 f16x8 __attribute__((ext_vector_type(8)));
typedef float    f32x4  __attribute__((ext_vector_type(4)));
typedef float    f32x16 __attribute__((ext_vector_type(16)));

typedef const __attribute__((address_space(1))) unsigned int gu32;
typedef       __attribute__((address_space(3))) unsigned int lu32;

// 2-level fp16 split: v = h + m + r, |r| <= 2^-22 |v|. v - (float)h is exact.
__device__ __forceinline__ void split2(float v, _Float16& h, _Float16& m) {
    h = (_Float16)v;
    m = (_Float16)(v - (float)h);
}

__device__ __forceinline__ unsigned short f16bits(_Float16 h) {
    union { _Float16 f; unsigned short u; } c; c.f = h; return c.u;
}

// ---------------------------------------------------------------------------
// Prep: w*2048 -> 2-level fp16, 32x32x16 B-fragment-linear layout:
// frag (s16 = k/16, nt = e/32) is 64 lanes x 8 f16; lane = (k/8 % 2)*32 + e%32,
// j = k%8.  offset = ((s16*2+nt)*64 + lane)*8 + j   (+ lev*WLVL)
// ---------------------------------------------------------------------------
__global__ __launch_bounds__(64)
void prep_w(const float* __restrict__ w, unsigned short* __restrict__ wre) {
    int gid = blockIdx.x * 64 + threadIdx.x;   // 16384 threads, 8 elems each
    int e  = gid >> 8;
    int kb = gid & 255;
    int k  = kb * 8;
    const float* wp = w + (size_t)e * DDIM + k;
    float4 f0 = *(const float4*)(wp);
    float4 f1 = *(const float4*)(wp + 4);
    float av[8] = {f0.x, f0.y, f0.z, f0.w, f1.x, f1.y, f1.z, f1.w};

    int s16 = kb >> 1;                 // k/16
    int hi  = kb & 1;                  // (k/8)%2
    int nt  = e >> 5;
    int lane = hi * 32 + (e & 31);
    size_t off = ((size_t)(s16 * 2 + nt) * 64 + lane) * 8;

    unsigned short hb[8], mb[8];
    #pragma unroll
    for (int j = 0; j < 8; ++j) {
        _Float16 h, m;
        split2(av[j] * WSCALE, h, m);
        hb[j] = f16bits(h); mb[j] = f16bits(m);
    }

    #pragma unroll
    for (int lev = 0; lev < 2; ++lev) {
        const unsigned short* src = lev ? mb : hb;
        uint4 v;
        v.x = (unsigned)src[0] | ((unsigned)src[1] << 16);
        v.y = (unsigned)src[2] | ((unsigned)src[3] << 16);
        v.z = (unsigned)src[4] | ((unsigned)src[5] << 16);
        v.w = (unsigned)src[6] | ((unsigned)src[7] << 16);
        *(uint4*)(wre + (size_t)lev * WLVL + off) = v;
    }
}

// ---------------------------------------------------------------------------
// Fused GEMM + epilogue. 512 blocks x 512 threads (8 waves), 2 blocks/CU.
// Block = 32 tokens; wave w = K-slice [w*256, w*256+256).
//
// KEY CHANGE vs previous: A-staging is now FULLY COALESCED.  Old mapping
// (lane -> token row) made every wave-level load 32 scattered 32B
// transactions (rows are 8 KB apart) -- a request-rate wall shared by all
// five ~75us variants.  New stage op i covers 8 COMPLETE rows: lane l ->
// row 8i+(l>>3), granule (l&7), i.e. 8 contiguous 128B segments per op.
// Granule is XOR-swizzled on the GLOBAL SOURCE (g ^= row&7; same 128B
// segment, permuted lanes -> coalescing preserved; rule #21: linear LDS
// dest + inverse-swizzled source + swizzled read).  LDS read applies the
// same XOR -> ~4-way bank conflict (1.58x, acceptable).
// B: depth-1 register ring, pinned with sched_barrier(0) (no JIT B stall).
// ---------------------------------------------------------------------------
__global__ __launch_bounds__(512, 4)
void router_fused(const float* __restrict__ x,
                  const unsigned short* __restrict__ wre,
                  const float* __restrict__ bias,
                  float* __restrict__ out,
                  int* __restrict__ histp,
                  float* __restrict__ entp)
{
    union SMem {
        float As[2][8192];            // [buf][wid*1024 + (row*8+g)*4f], 64 KB
        struct {
            float pl[16][16][64];     // [w*2+nt][reg][lane] partials, 64 KB
            float sct[NE][BT + 1];    // scores [expert][token]
            float bsh[NE];
            int   hist[NE];
            float entw[2];
        } ep;                          // ~74.5 KB -> 2 blocks/CU
    };
    __shared__ SMem sm;

    const int tid  = threadIdx.x;
    const int lane = tid & 63;
    const int wid  = tid >> 6;      // K-slice 0..7
    const int t0b  = blockIdx.x * BT;
    const int row  = lane & 31;     // token row in A fragment
    const int hi   = lane >> 5;     // k-subgroup

    if (tid < NE) { sm.ep.bsh[tid] = bias[tid]; sm.ep.hist[tid] = 0; }

    // Staging source: lane l covers row (l>>3) (+8 per op), granule
    // (l&7)^((l>>3)&7)  (XOR pre-swizzle; 128B segment per 8 lanes).
    const float* xrow = x + (size_t)(t0b + (lane >> 3)) * DDIM + wid * KSL
                          + (((lane & 7) ^ ((lane >> 3) & 7)) << 2);
    const unsigned short* wl = wre + (size_t)lane * 8;
    const int s16b = wid * NST;     // global 16-K step base

    f32x16 acc[2];
    #pragma unroll
    for (int i = 0; i < 16; ++i) { acc[0][i] = 0.f; acc[1][i] = 0.f; }

    // Stage chunk c into buffer buf: 4 ops x 1 KB, each op = 8 full rows.
    // LDS slot (linear, = base + lane*16B): i*64 + l = (8i + l>>3)*8 + (l&7)
    // -> As4[row*8 + j] holds granule j ^ (row&7) of row `row`.
    auto stage = [&](int c, int buf) {
        #pragma unroll
        for (int i = 0; i < 4; ++i) {
            const float* g = xrow + (size_t)i * 8 * DDIM + c * 32;
            __builtin_amdgcn_global_load_lds((gu32*)g,
                (lu32*)&sm.As[buf][wid * 1024 + i * 256], 16, 0, 0);
        }
    };
    // B frags for 16-K step: [0]=bh nt0, [1]=bh nt1, [2]=bm nt0, [3]=bm nt1
    auto loadB = [&](int s, f16x8 (&B)[4]) {
        #pragma unroll
        for (int f = 0; f < 4; ++f)
            B[f] = *(const f16x8*)(wl + (size_t)(f >> 1) * WLVL
                                      + ((size_t)((s16b + s) * 2 + (f & 1)) << 9));
    };
    auto computeStep = [&](const float4* As4, int s, const f16x8 (&B)[4]) {
        const int g0 = s * 4 + hi * 2;
        float4 G0 = As4[(row << 3) + ( g0      ^ (row & 7))];  // swizzled read
        float4 G1 = As4[(row << 3) + ((g0 + 1) ^ (row & 7))];
        float av[8] = {G0.x, G0.y, G0.z, G0.w, G1.x, G1.y, G1.z, G1.w};
        f16x8 ah, am;
        #pragma unroll
        for (int j = 0; j < 8; ++j) {
            _Float16 h, m;
            split2(av[j] * XSCALE, h, m);
            ah[j] = h; am[j] = m;
        }
        #pragma unroll
        for (int nt = 0; nt < 2; ++nt) {
            acc[nt] = __builtin_amdgcn_mfma_f32_32x32x16_f16(ah, B[nt],     acc[nt], 0, 0, 0);
            acc[nt] = __builtin_amdgcn_mfma_f32_32x32x16_f16(am, B[nt],     acc[nt], 0, 0, 0);
            acc[nt] = __builtin_amdgcn_mfma_f32_32x32x16_f16(ah, B[2 + nt], acc[nt], 0, 0, 0);
            acc[nt] = __builtin_amdgcn_mfma_f32_32x32x16_f16(am, B[2 + nt], acc[nt], 0, 0, 0);
        }
    };

    f16x8 Bb[2][4];                  // step t lives in Bb[t&1]
    stage(0, 0);
    loadB(0, Bb[0]);
    __syncthreads();                 // vmcnt(0) drain: chunk 0 resident

    #pragma unroll
    for (int c = 0; c < NCH; ++c) {
        const int buf = c & 1;
        if (c + 1 < NCH) stage(c + 1, buf ^ 1);   // issue next chunk DMA
        const float4* As4 = (const float4*)&sm.As[buf][wid * 1024];
        // step 0 of chunk: prefetch B for step 1, pin, compute
        loadB(c * 2 + 1, Bb[1]);
        __builtin_amdgcn_sched_barrier(0);
        computeStep(As4, 0, Bb[0]);
        // step 1: prefetch B for next chunk's step 0, pin, compute
        if (c + 1 < NCH) loadB(c * 2 + 2, Bb[0]);
        __builtin_amdgcn_sched_barrier(0);
        computeStep(As4, 1, Bb[1]);
        __syncthreads();             // one drain/chunk: waits chunk c+1 DMA
    }

    // ---- epilogue (As dead; pl overlays it) ----
    // C/D: col(expert%32)=lane&31, row(token)=(reg&3)+8*(reg>>2)+4*(lane>>5).
    #pragma unroll
    for (int nt = 0; nt < 2; ++nt)
        #pragma unroll
        for (int r = 0; r < 16; ++r)
            sm.ep.pl[wid * 2 + nt][r][lane] = acc[nt][r];
    __syncthreads();

    // Combine 8 K-slices (fixed order), sigmoid, score store (coalesced).
    {
        const int tok = tid >> 4;               // 0..31
        const int e0  = (tid & 15) * 4;         // 0..60
        const int nt  = e0 >> 5;
        const int r   = (tok & 3) | ((tok >> 3) << 2);
        const int ln  = ((tok >> 2) & 1) * 32 + (e0 & 31);
        f32x4 s4 = {0.f, 0.f, 0.f, 0.f};
        #pragma unroll
        for (int w = 0; w < 8; ++w)
            s4 += *(const f32x4*)&sm.ep.pl[w * 2 + nt][r][ln];
        float4 sv;
        sv.x = 1.0f / (1.0f + expf(-s4[0] * LUNSCALE));
        sv.y = 1.0f / (1.0f + expf(-s4[1] * LUNSCALE));
        sv.z = 1.0f / (1.0f + expf(-s4[2] * LUNSCALE));
        sv.w = 1.0f / (1.0f + expf(-s4[3] * LUNSCALE));
        sm.ep.sct[e0 + 0][tok] = sv.x;
        sm.ep.sct[e0 + 1][tok] = sv.y;
        sm.ep.sct[e0 + 2][tok] = sv.z;
        sm.ep.sct[e0 + 3][tok] = sv.w;
        *(float4*)&out[OFF_SC + (size_t)(t0b + tok) * NE + e0] = sv;
    }
    __syncthreads();

    // Top-8: waves 0-1; lane = expert-group x 16 tokens.
    float entv = 0.f;
    if (wid < 2) {
        const int tl = wid * 16 + (lane & 15);
        const int eg = lane >> 4;               // expert group of 16
        float v[16];
        #pragma unroll
        for (int i = 0; i < 16; ++i)
            v[i] = sm.ep.sct[eg * 16 + i][tl] + sm.ep.bsh[eg * 16 + i];

        float ch[TK]; int ci[TK]; float ssum = 0.f;
        #pragma unroll
        for (int p = 0; p < TK; ++p) {
            float bv = v[0]; int bi = 0;
            #pragma unroll
            for (int i = 1; i < 16; ++i) {      // strict '>': lowest idx on tie
                const bool sgt = v[i] > bv;
                bv = sgt ? v[i] : bv;
                bi = sgt ? i : bi;
            }
            int be = eg * 16 + bi;
            {   // combine groups: lane^16 (same token, other group)
                float ov = __shfl_xor(bv, 16);
                int   oe = __shfl_xor(be, 16);
                const bool tk = (ov > bv) || (ov == bv && oe < be);
                bv = tk ? ov : bv; be = tk ? oe : be;
            }
            {   // lane^32
                float ov = __shfl_xor(bv, 32);
                int   oe = __shfl_xor(be, 32);
                const bool tk = (ov > bv) || (ov == bv && oe < be);
                bv = tk ? ov : bv; be = tk ? oe : be;
            }
            #pragma unroll
            for (int i = 0; i < 16; ++i)        // static-index mask (rule #20)
                v[i] = (be == eg * 16 + i) ? -1e30f : v[i];
            const float sc = sm.ep.sct[be][tl]; // unbiased score
            ch[p] = sc; ci[p] = be; ssum += sc;
        }
        if (eg == 0) {
            const float inv = 1.0f / (ssum + 1e-20f);
            #pragma unroll
            for (int p = 0; p < TK; ++p) {
                atomicAdd(&sm.ep.hist[ci[p]], 1);
                const float pn = ch[p] * inv;   // ROUTE_SCALE == 1.0
                out[OFF_TOP + (size_t)(t0b + tl) * TK + p] = pn;
                out[OFF_IDX + (size_t)(t0b + tl) * TK + p] = (float)ci[p];
                entv += pn * logf(pn);
            }
        }
        entv += __shfl_down(entv, 8);
        entv += __shfl_down(entv, 4);
        entv += __shfl_down(entv, 2);
        entv += __shfl_down(entv, 1);
        if (lane == 0) sm.ep.entw[wid] = entv;
    }
    __syncthreads();

    if (tid == 0) entp[blockIdx.x] = sm.ep.entw[0] + sm.ep.entw[1];
    if (tid < NE && sm.ep.hist[tid] > 0)
        atomicAdd(&histp[(blockIdx.x & (NHC - 1)) * NE + tid], sm.ep.hist[tid]);
}

// ---------------------------------------------------------------------------
// Finalize: reduce histogram banks and entropy partials (deterministic)
// ---------------------------------------------------------------------------
__global__ __launch_bounds__(256)
void finalize(const int* __restrict__ histp,
              const float* __restrict__ entp,
              float* __restrict__ out)
{
    const int tid = threadIdx.x;
    if (tid < NE) {
        int s = 0;
        #pragma unroll
        for (int c = 0; c < NHC; ++c) s += histp[c * NE + tid];
        out[OFF_HIST + tid] = (float)s;
    }
    __shared__ float red[256];
    float e = 0.f;
    for (int i = tid; i < NBLK; i += 256) e += entp[i];
    red[tid] = e;
    __syncthreads();
    #pragma unroll
    for (int o = 128; o > 0; o >>= 1) {
        if (tid < o) red[tid] += red[tid + o];
        __syncthreads();
    }
    if (tid == 0) out[OFF_ENT] = -red[0] * (1.0f / (float)N_TOK);
}

extern "C" void kernel_launch(void* const* d_in, const int* in_sizes, int n_in,
                              void* d_out, int out_size, void* d_ws, size_t ws_size,
                              hipStream_t stream) {
    const float* x    = (const float*)d_in[0];   // [16384, 2048]
    const float* w    = (const float*)d_in[1];   // [64, 2048]
    const float* bias = (const float*)d_in[2];   // [64]
    float* out = (float*)d_out;
    unsigned short* wre = (unsigned short*)d_ws;            // 512 KB (2 levels)
    int*   histp = (int*)  ((char*)d_ws + HISTP_OFF);
    float* entp  = (float*)((char*)d_ws + ENTP_OFF);

    hipMemsetAsync(histp, 0, NHC * NE * sizeof(int), stream);

    prep_w      <<<dim3(256),  dim3(64),  0, stream>>>(w, wre);
    router_fused<<<dim3(NBLK), dim3(512), 0, stream>>>(x, wre, bias, out, histp, entp);
    finalize    <<<dim3(1),    dim3(256), 0, stream>>>(histp, entp, out);
}